// Round 3
// baseline (552.663 us; speedup 1.0000x reference)
//
#include <hip/hip_runtime.h>

#define NT 16384   // tokens
#define DM 4096    // d_model
#define NE 64      // experts
#define TPB 64     // tokens per block (one per lane)
#define NWAVE 8    // waves per block
#define EPW 8      // experts per wave
#define BK 64      // K per LDS tile
#define NTILE (DM / BK)

typedef __attribute__((address_space(3))) float lds_f;
typedef __attribute__((address_space(1))) const float glb_f;

// Block: 512 threads. lane <-> token; wave w <-> experts [8w,8w+8).
// W: wave-uniform global_load_dwordx4 into VGPRs (address kept in VGPRs via
// non-readfirstlane wv so the compiler can't scalarize -> deep VGPR prefetch).
// x: global_load_lds (width 16) into linear LDS with pre-swizzled global source;
// compute reads ds_read_b128 at byte ^ ((row&7)<<4) -> bank-conflict-free.
// Accuracy: f32 per-tile accumulation drained into f64 (validated, absmax 0).
__launch_bounds__(512, 2)
__global__ void moe_gate_main(const float* __restrict__ x,
                              const float* __restrict__ W,
                              float* __restrict__ out,
                              float* __restrict__ bsum) {
  __shared__ float xs[2][TPB][BK];      // 32 KiB, XOR-swizzled 16B chunks
  __shared__ float lg_s[TPB][NE + 1];   // 16.6 KiB
  __shared__ float esums[NWAVE][NE];    // 2 KiB

  const int tid  = threadIdx.x;
  const int lane = tid & 63;
  const int wvu  = __builtin_amdgcn_readfirstlane(tid >> 6);
  const int wv_v = tid >> 6;            // NOT readfirstlane: keeps W addrs in VGPRs
  const int blk  = blockIdx.x;

  // ---- staging precompute (2 glds calls/thread, 16B each) ----
  // LDS linear chunk index = wv*128 + q*64 + lane; row = idx/16, c_lin = lane&15.
  // Stored content chunk c_src = c_lin ^ (row&7)  (involution; read side XORs too).
  const int r0 = wvu * 8 + (lane >> 4);            // q=0 row; q=1 row = r0+4
  const int c0 = (lane & 15) ^ (r0 & 7);           // q=1 chunk = c0^4
  const float* gp0 = x + (size_t)(blk * TPB + r0) * DM + c0 * 4;
  const float* gp1 = x + (size_t)(blk * TPB + r0 + 4) * DM + (c0 ^ 4) * 4;
  float* lb0 = &xs[0][0][0] + wvu * 512;           // wave-uniform LDS base (floats)

  const float* Wb = W + (size_t)(wv_v * EPW) * DM; // per-thread (vector) W base

  double accd[EPW];
#pragma unroll
  for (int j = 0; j < EPW; ++j) accd[j] = 0.0;

  // stage tile 0 -> buf 0
  __builtin_amdgcn_global_load_lds((const glb_f*)gp0, (lds_f*)lb0, 16, 0, 0);
  __builtin_amdgcn_global_load_lds((const glb_f*)gp1, (lds_f*)(lb0 + 256), 16, 0, 0);
  __syncthreads();

  const unsigned xb_lane = (unsigned)(lane * 256 + ((lane & 7) << 4));  // byte base

  for (int t = 0; t < NTILE; ++t) {
    const int b = t & 1;
    if (t + 1 < NTILE) {                 // issue next-tile stage (async, other buf)
      const int nb = (t + 1) & 1;
      const float* g0 = gp0 + (size_t)(t + 1) * BK;
      const float* g1 = gp1 + (size_t)(t + 1) * BK;
      float* lb = lb0 + nb * 4096;
      __builtin_amdgcn_global_load_lds((const glb_f*)g0, (lds_f*)lb, 16, 0, 0);
      __builtin_amdgcn_global_load_lds((const glb_f*)g1, (lds_f*)(lb + 256), 16, 0, 0);
    }

    float accf[EPW];
#pragma unroll
    for (int j = 0; j < EPW; ++j) accf[j] = 0.f;

    const char* xsb = (const char*)&xs[b][0][0];
    const float* Wk = Wb + t * BK;
#pragma unroll
    for (int c = 0; c < 16; ++c) {
      const float4 xv = *(const float4*)(xsb + (xb_lane ^ (unsigned)(c << 4)));
#pragma unroll
      for (int j = 0; j < EPW; ++j) {
        const float4 wj = *(const float4*)(Wk + (size_t)j * DM + c * 4);
        accf[j] = fmaf(xv.x, wj.x, accf[j]);
        accf[j] = fmaf(xv.y, wj.y, accf[j]);
        accf[j] = fmaf(xv.z, wj.z, accf[j]);
        accf[j] = fmaf(xv.w, wj.w, accf[j]);
      }
    }
#pragma unroll
    for (int j = 0; j < EPW; ++j) accd[j] += (double)accf[j];

    __syncthreads();   // drains glds (vmcnt0) + protects buffer reuse
  }

  // dump logits -> lg_s[tok][expert]
#pragma unroll
  for (int j = 0; j < EPW; ++j) lg_s[lane][wvu * EPW + j] = (float)accd[j];
  __syncthreads();

  // Epilogue: wave wvu handles tokens [wvu*8, wvu*8+8); lane <-> expert now.
  float esum = 0.f;
  for (int ti = 0; ti < 8; ++ti) {
    const int t = wvu * 8 + ti;
    const float lg = lg_s[t][lane];

    float m = lg;
#pragma unroll
    for (int off = 32; off; off >>= 1) m = fmaxf(m, __shfl_xor(m, off, 64));
    const float p = __expf(lg - m);
    float Z = p;
#pragma unroll
    for (int off = 32; off; off >>= 1) Z += __shfl_xor(Z, off, 64);
    const float s = p / Z;
    esum += s;

    // top-1 (value desc, index asc — matches lax.top_k tie-break)
    float v1 = s; int i1 = lane;
#pragma unroll
    for (int off = 32; off; off >>= 1) {
      const float ov = __shfl_xor(v1, off, 64);
      const int   oi = __shfl_xor(i1, off, 64);
      if (ov > v1 || (ov == v1 && oi < i1)) { v1 = ov; i1 = oi; }
    }
    float sv = (lane == i1) ? -1.f : s;
    float v2 = sv; int i2 = lane;
#pragma unroll
    for (int off = 32; off; off >>= 1) {
      const float ov = __shfl_xor(v2, off, 64);
      const int   oi = __shfl_xor(i2, off, 64);
      if (ov > v2 || (ov == v2 && oi < i2)) { v2 = ov; i2 = oi; }
    }

    if (lane == 0) {
      const int gt = blk * TPB + t;
      const float inv = 1.f / (v1 + v2);
      out[2 * gt]              = v1 * inv;
      out[2 * gt + 1]          = v2 * inv;
      out[2 * NT + 2 * gt]     = (float)i1;
      out[2 * NT + 2 * gt + 1] = (float)i2;
    }
  }

  // per-block expert score sums (deterministic tree reduce, no atomics)
  esums[wvu][lane] = esum;
  __syncthreads();
  if (wvu == 0) {
    float tot = 0.f;
#pragma unroll
    for (int w = 0; w < NWAVE; ++w) tot += esums[w][lane];
    bsum[blk * NE + lane] = tot;
  }
}

// Reduce 256 per-block expert sums -> load balancing loss
__global__ void moe_gate_loss(const float* __restrict__ bsum,
                              float* __restrict__ out) {
  __shared__ float red[4][64];
  const int e = threadIdx.x & 63;
  const int g = threadIdx.x >> 6;
  float s = 0.f;
  for (int b = g; b < 256; b += 4) s += bsum[b * 64 + e];
  red[g][e] = s;
  __syncthreads();
  if (threadIdx.x < 64) {
    const float tot = red[0][e] + red[1][e] + red[2][e] + red[3][e];
    const float p = tot * (1.f / (float)NT);
    float term = p * logf(p + 1e-8f);
#pragma unroll
    for (int off = 32; off; off >>= 1) term += __shfl_xor(term, off, 64);
    if (e == 0) out[4 * NT] = term;  // out[65536]
  }
}

extern "C" void kernel_launch(void* const* d_in, const int* in_sizes, int n_in,
                              void* d_out, int out_size, void* d_ws, size_t ws_size,
                              hipStream_t stream) {
  const float* x = (const float*)d_in[0];   // [16384, 4096]
  const float* W = (const float*)d_in[1];   // [64, 4096]
  float* out = (float*)d_out;               // scores[32768] | idx[32768] | loss[1]
  float* bsum = (float*)d_ws;               // [256][64] per-block expert sums

  hipLaunchKernelGGL(moe_gate_main, dim3(NT / TPB), dim3(512), 0, stream, x, W, out, bsum);
  hipLaunchKernelGGL(moe_gate_loss, dim3(1), dim3(256), 0, stream, bsum, out);
}

// Round 4
// 215.757 us; speedup vs baseline: 2.5615x; 2.5615x over previous
//
#include <hip/hip_runtime.h>

#define NT 16384   // tokens
#define DM 4096    // d_model
#define NE 64      // experts
#define TTOK 16    // tokens per block (2 groups of 8)
#define EHALF 32   // experts per block (half of 64)

__device__ __forceinline__ int bitrev6(int l) {
  return ((l & 1) << 5) | ((l & 2) << 3) | ((l & 4) << 1) |
         ((l & 8) >> 1) | ((l & 16) >> 3) | ((l & 32) >> 5);
}

// Kernel 1: logits GEMM. Thread = 8 tok x 8 exp x 64-k lane slice.
// All operands per-lane float4, wave-coalesced (lane l reads k = l*4 + c*256).
// No LDS, no barriers. A/B double-buffered frags hide HBM/L2 latency.
// Accuracy: f32 sequential over 64 k per lane (validated granularity) +
// 6-level f32 butterfly tree across lanes (~1e-7, tree < sequential error).
__launch_bounds__(512, 2)
__global__ void moe_logits(const float* __restrict__ x,
                           const float* __restrict__ W,
                           float* __restrict__ logits) {
  const int tid  = threadIdx.x;
  const int lane = tid & 63;
  const int wv   = tid >> 6;
  const int bid  = blockIdx.x;

  // bid bits: [2:0]=tokTile low, [3]=expert half, [10:4]=tokTile high.
  // Blocks b and b+8 share the x tile and land on the same XCD (bid%8).
  const int h       = (bid >> 3) & 1;
  const int tokTile = (bid & 7) | ((bid >> 4) << 3);
  const int tokgrp  = wv >> 2;   // 0..1
  const int egrp    = wv & 3;    // 0..3

  const int tok0 = tokTile * TTOK + tokgrp * 8;
  const int e0   = h * EHALF + egrp * 8;

  const float* xp[8];
  const float* wp[8];
#pragma unroll
  for (int t = 0; t < 8; ++t) xp[t] = x + (size_t)(tok0 + t) * DM + lane * 4;
#pragma unroll
  for (int e = 0; e < 8; ++e) wp[e] = W + (size_t)(e0 + e) * DM + lane * 4;

  float acc[64];
#pragma unroll
  for (int i = 0; i < 64; ++i) acc[i] = 0.f;

  float4 xA[8], wA[8], xB[8], wB[8];
#pragma unroll
  for (int t = 0; t < 8; ++t) xA[t] = *(const float4*)(xp[t]);
#pragma unroll
  for (int e = 0; e < 8; ++e) wA[e] = *(const float4*)(wp[e]);

  for (int cp = 0; cp < 8; ++cp) {
    // issue B loads (chunk 2cp+1)
    {
      const size_t off = (size_t)(2 * cp + 1) * 256;
#pragma unroll
      for (int t = 0; t < 8; ++t) xB[t] = *(const float4*)(xp[t] + off);
#pragma unroll
      for (int e = 0; e < 8; ++e) wB[e] = *(const float4*)(wp[e] + off);
    }
    // compute A (chunk 2cp)
#pragma unroll
    for (int t = 0; t < 8; ++t)
#pragma unroll
      for (int e = 0; e < 8; ++e) {
        float a = acc[t * 8 + e];
        a = fmaf(xA[t].x, wA[e].x, a);
        a = fmaf(xA[t].y, wA[e].y, a);
        a = fmaf(xA[t].z, wA[e].z, a);
        a = fmaf(xA[t].w, wA[e].w, a);
        acc[t * 8 + e] = a;
      }
    // issue A loads (chunk 2cp+2)
    if (cp < 7) {
      const size_t off = (size_t)(2 * cp + 2) * 256;
#pragma unroll
      for (int t = 0; t < 8; ++t) xA[t] = *(const float4*)(xp[t] + off);
#pragma unroll
      for (int e = 0; e < 8; ++e) wA[e] = *(const float4*)(wp[e] + off);
    }
    // compute B (chunk 2cp+1)
#pragma unroll
    for (int t = 0; t < 8; ++t)
#pragma unroll
      for (int e = 0; e < 8; ++e) {
        float a = acc[t * 8 + e];
        a = fmaf(xB[t].x, wB[e].x, a);
        a = fmaf(xB[t].y, wB[e].y, a);
        a = fmaf(xB[t].z, wB[e].z, a);
        a = fmaf(xB[t].w, wB[e].w, a);
        acc[t * 8 + e] = a;
      }
  }

  // butterfly all-reduce-to-distinct-lanes: after 6 levels, lane l holds the
  // total for acc index bitrev6(l) in acc[0].
#pragma unroll
  for (int s = 0; s < 6; ++s) {
    const int n = 32 >> s;
    const bool hi = (lane >> s) & 1;
#pragma unroll
    for (int i = 0; i < n; ++i) {
      const float mine  = hi ? acc[i] : acc[i + n];
      const float keep  = hi ? acc[i + n] : acc[i];
      const float other = __shfl_xor(mine, 1 << s, 64);
      acc[i] = keep + other;
    }
  }

  const int a   = bitrev6(lane);
  const int tok = tok0 + (a >> 3);
  const int ex  = e0 + (a & 7);
  logits[(size_t)tok * NE + ex] = acc[0];
}

// Kernel 2: softmax + top-2 + per-block expert sums (R2-validated epilogue,
// reading logits from global). Grid 256 x 512 threads; wave wv owns 8 tokens.
__launch_bounds__(512, 2)
__global__ void moe_topk(const float* __restrict__ logits,
                         float* __restrict__ out,
                         float* __restrict__ bsum) {
  __shared__ float esums[8][64];
  const int tid  = threadIdx.x;
  const int lane = tid & 63;
  const int wv   = tid >> 6;
  const int blk  = blockIdx.x;

  float esum = 0.f;
  for (int ti = 0; ti < 8; ++ti) {
    const int t = blk * 64 + wv * 8 + ti;
    const float lg = logits[(size_t)t * NE + lane];

    float m = lg;
#pragma unroll
    for (int off = 32; off; off >>= 1) m = fmaxf(m, __shfl_xor(m, off, 64));
    const float p = __expf(lg - m);
    float Z = p;
#pragma unroll
    for (int off = 32; off; off >>= 1) Z += __shfl_xor(Z, off, 64);
    const float s = p / Z;
    esum += s;

    // top-1 (value desc, index asc — matches lax.top_k tie-break)
    float v1 = s; int i1 = lane;
#pragma unroll
    for (int off = 32; off; off >>= 1) {
      const float ov = __shfl_xor(v1, off, 64);
      const int   oi = __shfl_xor(i1, off, 64);
      if (ov > v1 || (ov == v1 && oi < i1)) { v1 = ov; i1 = oi; }
    }
    // top-2: mask winner (scores >= 0, so -1 acts as -inf)
    float sv = (lane == i1) ? -1.f : s;
    float v2 = sv; int i2 = lane;
#pragma unroll
    for (int off = 32; off; off >>= 1) {
      const float ov = __shfl_xor(v2, off, 64);
      const int   oi = __shfl_xor(i2, off, 64);
      if (ov > v2 || (ov == v2 && oi < i2)) { v2 = ov; i2 = oi; }
    }

    if (lane == 0) {
      const float inv = 1.f / (v1 + v2);
      out[2 * t]              = v1 * inv;
      out[2 * t + 1]          = v2 * inv;
      out[2 * NT + 2 * t]     = (float)i1;
      out[2 * NT + 2 * t + 1] = (float)i2;
    }
  }

  esums[wv][lane] = esum;
  __syncthreads();
  if (wv == 0) {
    float tot = 0.f;
#pragma unroll
    for (int w = 0; w < 8; ++w) tot += esums[w][lane];
    bsum[blk * NE + lane] = tot;
  }
}

// Kernel 3: reduce 256 per-block expert sums -> load balancing loss
__global__ void moe_gate_loss(const float* __restrict__ bsum,
                              float* __restrict__ out) {
  __shared__ float red[4][64];
  const int e = threadIdx.x & 63;
  const int g = threadIdx.x >> 6;
  float s = 0.f;
  for (int b = g; b < 256; b += 4) s += bsum[b * 64 + e];
  red[g][e] = s;
  __syncthreads();
  if (threadIdx.x < 64) {
    const float tot = red[0][e] + red[1][e] + red[2][e] + red[3][e];
    const float p = tot * (1.f / (float)NT);
    float term = p * logf(p + 1e-8f);
#pragma unroll
    for (int off = 32; off; off >>= 1) term += __shfl_xor(term, off, 64);
    if (e == 0) out[4 * NT] = term;  // out[65536]
  }
}

extern "C" void kernel_launch(void* const* d_in, const int* in_sizes, int n_in,
                              void* d_out, int out_size, void* d_ws, size_t ws_size,
                              hipStream_t stream) {
  const float* x = (const float*)d_in[0];   // [16384, 4096]
  const float* W = (const float*)d_in[1];   // [64, 4096]
  float* out = (float*)d_out;               // scores[32768] | idx[32768] | loss[1]
  float* logits = (float*)d_ws;             // [16384][64] f32 = 4 MiB
  float* bsum = logits + (size_t)NT * NE;   // [256][64]

  hipLaunchKernelGGL(moe_logits, dim3((NT / TTOK) * 2), dim3(512), 0, stream, x, W, logits);
  hipLaunchKernelGGL(moe_topk, dim3(NT / 64), dim3(512), 0, stream, logits, out, bsum);
  hipLaunchKernelGGL(moe_gate_loss, dim3(1), dim3(256), 0, stream, bsum, out);
}